// Round 3
// baseline (2799.396 us; speedup 1.0000x reference)
//
#include <hip/hip_runtime.h>
#include <stdint.h>

typedef _Float16 half_t;
typedef _Float16 half4 __attribute__((ext_vector_type(4)));
typedef _Float16 half8 __attribute__((ext_vector_type(8)));
typedef float floatx4 __attribute__((ext_vector_type(4)));

#define D_MODEL 1024
#define NHEAD 8
#define DHEAD 128
#define FF_DIM 2048
#define NLAYER 3
#define BATCH 8
#define TSEQ 256
#define USEQ 1024
#define TPAD 128256
#define UPAD 10000
#define TEMP_ 5e-4f
#define SCALE_QK 0.08838834764831845f

// ---------------- wave (64-lane) shuffle-only reductions ----------------
__device__ inline float wv_sum(float v) {
#pragma unroll
  for (int o = 32; o; o >>= 1) v += __shfl_xor(v, o, 64);
  return v;
}
__device__ inline float wv_max(float v) {
#pragma unroll
  for (int o = 32; o; o >>= 1) v = fmaxf(v, __shfl_xor(v, o, 64));
  return v;
}

// ---------------- async global->LDS staging (width 16) ----------------
typedef const __attribute__((address_space(1))) uint32_t* gas1_u32;
typedef __attribute__((address_space(3))) uint32_t* las3_u32;
__device__ __forceinline__ void gload16(const half_t* g, half_t* l) {
  __builtin_amdgcn_global_load_lds((gas1_u32)g, (las3_u32)l, 16, 0, 0);
}

// ---------------- generic batched GEMM: C = alpha * A[M,K] * B[N,K]^T + bias ----------------
// A,B fp16 K-contiguous. z -> (zb = z/zdiv, zh = z%zdiv) offsets. M,N mult of 128; K mult of 64.
// Staging via global_load_lds width-16: LDS dest linear (wave-uniform base + lane*16);
// XOR swizzle (granule g of row r holds source granule g^(r&7)) applied on the GLOBAL source
// address, reads use the same XOR -> conflict-free ds_read_b128 (rule #21).
// If Vt != null: output columns >= 2*D_MODEL (the V part of a QKV projection) are written
// TRANSPOSED into Vt[(b*NHEAD+h)*DHEAD + d][s] instead of C (acc holds 4 contiguous rows
// per column -> half4 column store). Replaces the separate vtrans pass.
__global__ __launch_bounds__(256)
void gemm_bt_kernel(const half_t* __restrict__ A, long lda, long sAb, long sAz,
                    const half_t* __restrict__ B, long ldb, long sBb, long sBz,
                    float* __restrict__ Cf, half_t* __restrict__ Ch,
                    long ldc, long sCb, long sCz,
                    const float* __restrict__ bias,
                    half_t* __restrict__ Vt, int vtS,
                    int M, int N, int K, float alpha, int relu, int zdiv) {
  __shared__ __align__(16) half_t As[128 * 64];
  __shared__ __align__(16) half_t Bs[128 * 64];

  const int z = blockIdx.z;
  const int zb = z / zdiv, zh = z % zdiv;
  A += (long)zb * sAb + (long)zh * sAz;
  B += (long)zb * sBb + (long)zh * sBz;
  const long coff = (long)zb * sCb + (long)zh * sCz;

  const int tid = threadIdx.x;
  const int lane = tid & 63;
  const int wid = tid >> 6;
  const long row0 = (long)blockIdx.y * 128;
  const long col0 = (long)blockIdx.x * 128;

  // staging geometry: wave wid, iteration i covers rows [i*32 + wid*8, +8), 64 halves each.
  const int srw = lane >> 3;     // row within 8-row block
  const int sg = lane & 7;       // LDS granule (linear dest)

  const int wm = (wid & 1) << 6;
  const int wn = (wid >> 1) << 6;
  const int fm = lane & 15;
  const int quad = lane >> 4;

  floatx4 acc[4][4] = {};

  for (int k0 = 0; k0 < K; k0 += 64) {
#pragma unroll
    for (int i = 0; i < 4; ++i) {
      const int rb = (i << 5) + (wid << 3);   // wave-uniform row-block base
      const int rr = rb + srw;                // this lane's row
      const int gg = sg ^ (rr & 7);           // pre-swizzled source granule
      gload16(A + (row0 + rr) * lda + k0 + (gg << 3), &As[rb << 6]);
      gload16(B + (col0 + rr) * ldb + k0 + (gg << 3), &Bs[rb << 6]);
    }
    __syncthreads();
#pragma unroll
    for (int kk = 0; kk < 64; kk += 32) {
      const int gq = (kk >> 3) + quad;  // granule for this quad
      half8 af[4], bfr[4];
#pragma unroll
      for (int mi = 0; mi < 4; ++mi) {
        const int r = wm + (mi << 4) + fm;
        af[mi] = *(const half8*)(&As[(r << 6) + ((gq ^ (r & 7)) << 3)]);
      }
#pragma unroll
      for (int ni = 0; ni < 4; ++ni) {
        const int r = wn + (ni << 4) + fm;
        bfr[ni] = *(const half8*)(&Bs[(r << 6) + ((gq ^ (r & 7)) << 3)]);
      }
#pragma unroll
      for (int mi = 0; mi < 4; ++mi)
#pragma unroll
        for (int ni = 0; ni < 4; ++ni)
          acc[mi][ni] = __builtin_amdgcn_mfma_f32_16x16x32_f16(af[mi], bfr[ni], acc[mi][ni], 0, 0, 0);
    }
    __syncthreads();
  }

  // epilogue: C/D layout col = lane&15, row = quad*4 + r (m89/m91-verified)
#pragma unroll
  for (int ni = 0; ni < 4; ++ni) {
    const long colBase = col0 + wn + (ni << 4);   // wave-uniform 16-col block
    const long col = colBase + fm;
    const float bv = bias ? bias[col] : 0.0f;
    if (Vt && colBase >= 2 * D_MODEL) {
      // V part of QKV: write transposed, skip normal C write
      const int cc = (int)(colBase - 2 * D_MODEL) + fm;
      const int h = cc >> 7, dd = cc & 127;
#pragma unroll
      for (int mi = 0; mi < 4; ++mi) {
        const long s0 = row0 + wm + (mi << 4) + (quad << 2);
        const int bidx = (int)(s0 / vtS);
        const int ss = (int)(s0 - (long)bidx * vtS);
        half4 hv;
#pragma unroll
        for (int r = 0; r < 4; ++r) hv[r] = (half_t)(acc[mi][ni][r] * alpha + bv);
        *(half4*)(Vt + ((long)(bidx * NHEAD + h) * DHEAD + dd) * (long)vtS + ss) = hv;
      }
    } else {
#pragma unroll
      for (int mi = 0; mi < 4; ++mi) {
#pragma unroll
        for (int r = 0; r < 4; ++r) {
          const long row = row0 + wm + (mi << 4) + (quad << 2) + r;
          float v = acc[mi][ni][r] * alpha + bv;
          if (relu) v = fmaxf(v, 0.0f);
          const long idx = coff + row * ldc + col;
          if (Cf) Cf[idx] = v;
          if (Ch) Ch[idx] = (half_t)v;
        }
      }
    }
  }
}

// ---------------- elementwise / small kernels (wave-per-row, G13) ----------------
__global__ void cvt_kernel(const float* __restrict__ in, half_t* __restrict__ out, long n) {
  const long n4 = n >> 2;
  long i = (long)blockIdx.x * 256 + threadIdx.x;
  const long stride = (long)gridDim.x * 256;
  for (; i < n4; i += stride) {
    const float4 v = *(const float4*)(in + (i << 2));
    half4 h;
    h[0] = (half_t)v.x; h[1] = (half_t)v.y; h[2] = (half_t)v.z; h[3] = (half_t)v.w;
    *(half4*)(out + (i << 2)) = h;
  }
}

// 4 tokens per block, one wave each; 16 floats per lane.
__global__ __launch_bounds__(256) void embed_kernel(const int* __restrict__ tok,
                                                    const float* __restrict__ emb,
                                                    float* __restrict__ xf, half_t* __restrict__ xh) {
  const int wid = threadIdx.x >> 6, lane = threadIdx.x & 63;
  const long r = (long)blockIdx.x * 4 + wid;
  const long src = (long)tok[r] * D_MODEL;
  const int j0 = lane << 4;
#pragma unroll
  for (int c = 0; c < 4; ++c) {
    const int j = j0 + (c << 2);
    const float4 v = *(const float4*)(emb + src + j);
    *(float4*)(xf + r * D_MODEL + j) = v;
    half4 h;
    h[0] = (half_t)v.x; h[1] = (half_t)v.y; h[2] = (half_t)v.z; h[3] = (half_t)v.w;
    *(half4*)(xh + r * D_MODEL + j) = h;
  }
}

// x = LN(x + y) * s + b  (in-place on xf, also emits fp16 copy). 4 rows/block, wave-per-row.
__global__ __launch_bounds__(256) void ln_kernel(float* x, const float* y,
                                                 const float* s, const float* b, half_t* xh) {
  const int wid = threadIdx.x >> 6, lane = threadIdx.x & 63;
  const long row = (long)blockIdx.x * 4 + wid;
  float* xr = x + row * D_MODEL;
  const float* yr = y + row * D_MODEL;
  const int j0 = lane << 4;
  float v[16];
  float sum = 0.f, sq = 0.f;
#pragma unroll
  for (int c = 0; c < 4; ++c) {
    const int j = j0 + (c << 2);
    const float4 xv = *(const float4*)(xr + j);
    const float4 yv = *(const float4*)(yr + j);
    v[c * 4 + 0] = xv.x + yv.x; v[c * 4 + 1] = xv.y + yv.y;
    v[c * 4 + 2] = xv.z + yv.z; v[c * 4 + 3] = xv.w + yv.w;
#pragma unroll
    for (int k = 0; k < 4; ++k) { const float t = v[c * 4 + k]; sum += t; sq += t * t; }
  }
  sum = wv_sum(sum);
  sq = wv_sum(sq);
  const float mean = sum * (1.0f / D_MODEL);
  const float var = sq * (1.0f / D_MODEL) - mean * mean;
  const float inv = rsqrtf(var + 1e-5f);
#pragma unroll
  for (int c = 0; c < 4; ++c) {
    const int j = j0 + (c << 2);
    const float4 sv = *(const float4*)(s + j);
    const float4 bv = *(const float4*)(b + j);
    float4 ov;
    ov.x = (v[c * 4 + 0] - mean) * inv * sv.x + bv.x;
    ov.y = (v[c * 4 + 1] - mean) * inv * sv.y + bv.y;
    ov.z = (v[c * 4 + 2] - mean) * inv * sv.z + bv.z;
    ov.w = (v[c * 4 + 3] - mean) * inv * sv.w + bv.w;
    *(float4*)(xr + j) = ov;
    half4 h;
    h[0] = (half_t)ov.x; h[1] = (half_t)ov.y; h[2] = (half_t)ov.z; h[3] = (half_t)ov.w;
    *(half4*)(xh + row * D_MODEL + j) = h;
  }
}

// in-place masked softmax over rows of sc[z][q][S]; 4 rows/block, wave-per-row, shuffle-only.
__global__ __launch_bounds__(256) void softmax_kernel(half_t* sc, const int* __restrict__ tok,
                                                      int S, int padidx) {
  const int wid = threadIdx.x >> 6, lane = threadIdx.x & 63;
  const int q = blockIdx.x * 4 + wid, z = blockIdx.y;
  const int b = z >> 3;  // NHEAD == 8
  half_t* row = sc + (long)z * S * S + (long)q * S;
  const int* tb = tok + (long)b * S;
  if (S == 1024) {
    const int j0 = lane << 4;  // 16 elems/lane
    half8 h0 = *(const half8*)(row + j0);
    half8 h1 = *(const half8*)(row + j0 + 8);
    float v[16];
    float m = -3e38f;
#pragma unroll
    for (int c = 0; c < 4; ++c) {
      const int4 tk = *(const int4*)(tb + j0 + (c << 2));
      const int base = c << 2;
      const half8& hh = (c < 2) ? h0 : h1;
      const int hb = (c & 1) << 2;
      v[base + 0] = (tk.x == padidx) ? -1e9f : (float)hh[hb + 0];
      v[base + 1] = (tk.y == padidx) ? -1e9f : (float)hh[hb + 1];
      v[base + 2] = (tk.z == padidx) ? -1e9f : (float)hh[hb + 2];
      v[base + 3] = (tk.w == padidx) ? -1e9f : (float)hh[hb + 3];
#pragma unroll
      for (int k = 0; k < 4; ++k) m = fmaxf(m, v[base + k]);
    }
    m = wv_max(m);
    float ssum = 0.f;
#pragma unroll
    for (int i = 0; i < 16; ++i) { v[i] = expf(v[i] - m); ssum += v[i]; }
    ssum = wv_sum(ssum);
    const float inv = 1.0f / ssum;
    half8 o0, o1;
#pragma unroll
    for (int i = 0; i < 8; ++i) { o0[i] = (half_t)(v[i] * inv); o1[i] = (half_t)(v[8 + i] * inv); }
    *(half8*)(row + j0) = o0;
    *(half8*)(row + j0 + 8) = o1;
  } else {
    // S == 256: 4 elems/lane
    const int j0 = lane << 2;
    const half4 h = *(const half4*)(row + j0);
    const int4 tk = *(const int4*)(tb + j0);
    float v[4];
    v[0] = (tk.x == padidx) ? -1e9f : (float)h[0];
    v[1] = (tk.y == padidx) ? -1e9f : (float)h[1];
    v[2] = (tk.z == padidx) ? -1e9f : (float)h[2];
    v[3] = (tk.w == padidx) ? -1e9f : (float)h[3];
    float m = fmaxf(fmaxf(v[0], v[1]), fmaxf(v[2], v[3]));
    m = wv_max(m);
    float ssum = 0.f;
#pragma unroll
    for (int i = 0; i < 4; ++i) { v[i] = expf(v[i] - m); ssum += v[i]; }
    ssum = wv_sum(ssum);
    const float inv = 1.0f / ssum;
    half4 o;
#pragma unroll
    for (int i = 0; i < 4; ++i) o[i] = (half_t)(v[i] * inv);
    *(half4*)(row + j0) = o;
  }
}

__global__ __launch_bounds__(256) void rowsq_kernel(const float* __restrict__ x, float* __restrict__ o) {
  const int wid = threadIdx.x >> 6, lane = threadIdx.x & 63;
  const long row = (long)blockIdx.x * 4 + wid;
  const float* xr = x + row * D_MODEL;
  float s = 0.f;
#pragma unroll
  for (int c = 0; c < 4; ++c) {
    const float4 v = *(const float4*)(xr + (lane << 4) + (c << 2));
    s += v.x * v.x + v.y * v.y + v.z * v.z + v.w * v.w;
  }
  s = wv_sum(s);
  if (lane == 0) o[row] = s;
}

// out row currently holds cross[b,u,:]; transform to log_softmax(-TEMP*(un+tn-2c)) with pad mask
// 4 u-rows/block, wave-per-row (TSEQ=256 -> 4 floats/lane).
__global__ __launch_bounds__(256) void dist_lsm_kernel(float* out, const float* __restrict__ un,
                                                       const float* __restrict__ tn,
                                                       const int* __restrict__ utok,
                                                       const int* __restrict__ ttok) {
  const int wid = threadIdx.x >> 6, lane = threadIdx.x & 63;
  const int u = blockIdx.x * 4 + wid, b = blockIdx.y;
  const long off = ((long)(b * USEQ + u)) * TSEQ;
  const int j0 = lane << 2;
  const float4 c = *(const float4*)(out + off + j0);
  const float4 tv = *(const float4*)(tn + b * TSEQ + j0);
  const int4 tk = *(const int4*)(ttok + (long)b * TSEQ + j0);
  const float uv = un[b * USEQ + u];
  const bool upad = (utok[(long)b * USEQ + u] == UPAD);
  float x[4];
  x[0] = (upad || tk.x == TPAD) ? -1e9f : -TEMP_ * (uv + tv.x - 2.0f * c.x);
  x[1] = (upad || tk.y == TPAD) ? -1e9f : -TEMP_ * (uv + tv.y - 2.0f * c.y);
  x[2] = (upad || tk.z == TPAD) ? -1e9f : -TEMP_ * (uv + tv.z - 2.0f * c.z);
  x[3] = (upad || tk.w == TPAD) ? -1e9f : -TEMP_ * (uv + tv.w - 2.0f * c.w);
  float m = fmaxf(fmaxf(x[0], x[1]), fmaxf(x[2], x[3]));
  m = wv_max(m);
  float s = 0.f;
#pragma unroll
  for (int i = 0; i < 4; ++i) s += expf(x[i] - m);
  s = wv_sum(s);
  const float lse = m + logf(s);
  float4 o;
  o.x = x[0] - lse; o.y = x[1] - lse; o.z = x[2] - lse; o.w = x[3] - lse;
  *(float4*)(out + off + j0) = o;
}

// ---------------- host-side orchestration ----------------
static void launch_gemm(hipStream_t st, const half_t* A, long lda, long sAb, long sAz,
                        const half_t* B, long ldb, long sBb, long sBz,
                        float* Cf, half_t* Ch, long ldc, long sCb, long sCz,
                        const float* bias, half_t* Vt, int vtS,
                        int M, int N, int K, float alpha, int relu,
                        int zdiv, int nz) {
  dim3 g(N / 128, M / 128, nz), blk(256);
  gemm_bt_kernel<<<g, blk, 0, st>>>(A, lda, sAb, sAz, B, ldb, sBb, sBz,
                                    Cf, Ch, ldc, sCb, sCz, bias, Vt, vtS,
                                    M, N, K, alpha, relu, zdiv);
}

struct EncW {
  const int* tok; int S;
  const float *emb, *ipb, *ob, *l1s, *l1b, *f1b, *f2b, *l2s, *l2b;
  const half_t *ipw, *ow, *f1w, *f2w;
  int padidx;
};
struct Bufs {
  float *xf, *yf;
  half_t *xh, *qkv, *vt, *sc, *oh, *ffh;
};

static void run_encoder(hipStream_t st, const EncW& w, const Bufs& bb) {
  const int S = w.S, Ntok = BATCH * S;
  embed_kernel<<<Ntok / 4, 256, 0, st>>>(w.tok, w.emb, bb.xf, bb.xh);
  for (int l = 0; l < NLAYER; ++l) {
    // QKV projection -> qkv[Ntok, 3D] fp16 (Q,K parts); V part written transposed into vt
    launch_gemm(st, bb.xh, D_MODEL, 0, 0,
                w.ipw + (size_t)l * 3 * D_MODEL * D_MODEL, D_MODEL, 0, 0,
                nullptr, bb.qkv, 3 * D_MODEL, 0, 0,
                w.ipb + (size_t)l * 3 * D_MODEL, bb.vt, S,
                Ntok, 3 * D_MODEL, D_MODEL, 1.0f, 0, 1, 1);
    // scores = scale * Q K^T   (per z = b*H + h, strided into qkv)
    launch_gemm(st, bb.qkv, 3 * D_MODEL, (long)S * 3 * D_MODEL, DHEAD,
                bb.qkv + D_MODEL, 3 * D_MODEL, (long)S * 3 * D_MODEL, DHEAD,
                nullptr, bb.sc, S, (long)NHEAD * S * S, (long)S * S,
                nullptr, nullptr, 0,
                S, S, DHEAD, SCALE_QK, 0, NHEAD, BATCH * NHEAD);
    softmax_kernel<<<dim3(S / 4, BATCH * NHEAD), 256, 0, st>>>(bb.sc, w.tok, S, w.padidx);
    // O_head = P V  -> oh[Ntok, D] (heads concatenated)
    launch_gemm(st, bb.sc, S, (long)NHEAD * S * S, (long)S * S,
                bb.vt, S, (long)NHEAD * DHEAD * S, (long)DHEAD * S,
                nullptr, bb.oh, D_MODEL, (long)S * D_MODEL, DHEAD,
                nullptr, nullptr, 0,
                S, DHEAD, S, 1.0f, 0, NHEAD, BATCH * NHEAD);
    // output projection -> yf fp32
    launch_gemm(st, bb.oh, D_MODEL, 0, 0,
                w.ow + (size_t)l * D_MODEL * D_MODEL, D_MODEL, 0, 0,
                bb.yf, nullptr, D_MODEL, 0, 0,
                w.ob + (size_t)l * D_MODEL, nullptr, 0,
                Ntok, D_MODEL, D_MODEL, 1.0f, 0, 1, 1);
    ln_kernel<<<Ntok / 4, 256, 0, st>>>(bb.xf, bb.yf, w.l1s + (size_t)l * D_MODEL,
                                        w.l1b + (size_t)l * D_MODEL, bb.xh);
    // FF1 (+ReLU) -> ffh fp16
    launch_gemm(st, bb.xh, D_MODEL, 0, 0,
                w.f1w + (size_t)l * FF_DIM * D_MODEL, D_MODEL, 0, 0,
                nullptr, bb.ffh, FF_DIM, 0, 0,
                w.f1b + (size_t)l * FF_DIM, nullptr, 0,
                Ntok, FF_DIM, D_MODEL, 1.0f, 1, 1, 1);
    // FF2 -> yf fp32
    launch_gemm(st, bb.ffh, FF_DIM, 0, 0,
                w.f2w + (size_t)l * D_MODEL * FF_DIM, FF_DIM, 0, 0,
                bb.yf, nullptr, D_MODEL, 0, 0,
                w.f2b + (size_t)l * D_MODEL, nullptr, 0,
                Ntok, D_MODEL, FF_DIM, 1.0f, 0, 1, 1);
    ln_kernel<<<Ntok / 4, 256, 0, st>>>(bb.xf, bb.yf, w.l2s + (size_t)l * D_MODEL,
                                        w.l2b + (size_t)l * D_MODEL, bb.xh);
  }
}

extern "C" void kernel_launch(void* const* d_in, const int* in_sizes, int n_in,
                              void* d_out, int out_size, void* d_ws, size_t ws_size,
                              hipStream_t stream) {
  (void)in_sizes; (void)n_in; (void)out_size; (void)ws_size;
  const int* ttok = (const int*)d_in[0];
  const int* utok = (const int*)d_in[1];
  const float* tp[13];
  const float* up[13];
  for (int i = 0; i < 13; ++i) tp[i] = (const float*)d_in[2 + i];
  for (int i = 0; i < 13; ++i) up[i] = (const float*)d_in[15 + i];
  // index: 0 emb, 1 ipw, 2 ipb, 3 ow, 4 ob, 5 l1s, 6 l1b, 7 f1w, 8 f1b, 9 f2w, 10 f2b, 11 l2s, 12 l2b

  char* wp = (char*)d_ws;
  auto alloc = [&](size_t bytes) {
    void* p = wp;
    wp += (bytes + 255) & ~(size_t)255;
    return p;
  };
  const size_t IPW = (size_t)NLAYER * 3 * D_MODEL * D_MODEL;
  const size_t OW = (size_t)NLAYER * D_MODEL * D_MODEL;
  const size_t F1W = (size_t)NLAYER * FF_DIM * D_MODEL;
  const size_t F2W = (size_t)NLAYER * D_MODEL * FF_DIM;
  half_t* t_ipw = (half_t*)alloc(IPW * 2);
  half_t* t_ow = (half_t*)alloc(OW * 2);
  half_t* t_f1w = (half_t*)alloc(F1W * 2);
  half_t* t_f2w = (half_t*)alloc(F2W * 2);
  half_t* u_ipw = (half_t*)alloc(IPW * 2);
  half_t* u_ow = (half_t*)alloc(OW * 2);
  half_t* u_f1w = (half_t*)alloc(F1W * 2);
  half_t* u_f2w = (half_t*)alloc(F2W * 2);
  Bufs bb;
  bb.xf = (float*)alloc((size_t)BATCH * USEQ * D_MODEL * 4);
  bb.yf = (float*)alloc((size_t)BATCH * USEQ * D_MODEL * 4);
  bb.xh = (half_t*)alloc((size_t)BATCH * USEQ * D_MODEL * 2);
  bb.qkv = (half_t*)alloc((size_t)BATCH * USEQ * 3 * D_MODEL * 2);
  bb.vt = (half_t*)alloc((size_t)BATCH * NHEAD * DHEAD * USEQ * 2);
  bb.sc = (half_t*)alloc((size_t)BATCH * NHEAD * USEQ * USEQ * 2);
  bb.oh = (half_t*)alloc((size_t)BATCH * USEQ * D_MODEL * 2);
  bb.ffh = (half_t*)alloc((size_t)BATCH * USEQ * FF_DIM * 2);
  half_t* tfh = (half_t*)alloc((size_t)BATCH * TSEQ * D_MODEL * 2);
  float* tn = (float*)alloc((size_t)BATCH * TSEQ * 4);
  float* un = (float*)alloc((size_t)BATCH * USEQ * 4);

  // weight fp32 -> fp16
  cvt_kernel<<<1024, 256, 0, stream>>>(tp[1], t_ipw, (long)IPW);
  cvt_kernel<<<1024, 256, 0, stream>>>(tp[3], t_ow, (long)OW);
  cvt_kernel<<<1024, 256, 0, stream>>>(tp[7], t_f1w, (long)F1W);
  cvt_kernel<<<1024, 256, 0, stream>>>(tp[9], t_f2w, (long)F2W);
  cvt_kernel<<<1024, 256, 0, stream>>>(up[1], u_ipw, (long)IPW);
  cvt_kernel<<<1024, 256, 0, stream>>>(up[3], u_ow, (long)OW);
  cvt_kernel<<<1024, 256, 0, stream>>>(up[7], u_f1w, (long)F1W);
  cvt_kernel<<<1024, 256, 0, stream>>>(up[9], u_f2w, (long)F2W);

  // text encoder
  EncW tw{ttok, TSEQ, tp[0], tp[2], tp[4], tp[5], tp[6], tp[8], tp[10], tp[11], tp[12],
          t_ipw, t_ow, t_f1w, t_f2w, TPAD};
  run_encoder(stream, tw, bb);
  rowsq_kernel<<<BATCH * TSEQ / 4, 256, 0, stream>>>(bb.xf, tn);
  hipMemcpyAsync(tfh, bb.xh, (size_t)BATCH * TSEQ * D_MODEL * 2, hipMemcpyDeviceToDevice, stream);

  // unit encoder
  EncW uw{utok, USEQ, up[0], up[2], up[4], up[5], up[6], up[8], up[10], up[11], up[12],
          u_ipw, u_ow, u_f1w, u_f2w, UPAD};
  run_encoder(stream, uw, bb);
  rowsq_kernel<<<BATCH * USEQ / 4, 256, 0, stream>>>(bb.xf, un);

  // cross[b] = uf[b] @ tf[b]^T  -> d_out, then in-place dist + log_softmax
  float* out = (float*)d_out;
  launch_gemm(stream, bb.xh, D_MODEL, (long)USEQ * D_MODEL, 0,
              tfh, D_MODEL, (long)TSEQ * D_MODEL, 0,
              out, nullptr, TSEQ, (long)USEQ * TSEQ, 0,
              nullptr, nullptr, 0,
              USEQ, TSEQ, D_MODEL, 1.0f, 0, 1, BATCH);
  dist_lsm_kernel<<<dim3(USEQ / 4, BATCH), 256, 0, stream>>>(out, un, tn, utok, ttok);
}